// Round 2
// baseline (897.584 us; speedup 1.0000x reference)
//
#include <hip/hip_runtime.h>
#include <hip/hip_bf16.h>
#include <stdint.h>
#include <stddef.h>

// Problem dims (fixed by reference)
#define BSZ  8192
#define DIN  1024
#define HH   4096
#define DOUT 1024

// Old-kernel GEMM tile config (kept for fallback paths)
#define BM 128
#define BN 128
#define BK 32

typedef __attribute__((ext_vector_type(8))) short   frag8;   // 8 bf16 (4 VGPRs)
typedef __attribute__((ext_vector_type(4))) float   f32x4;   // MFMA C/D
typedef __attribute__((ext_vector_type(8))) unsigned short u16x8;

__device__ __forceinline__ unsigned short f2bf_rne(float f) {
    union { float f; uint32_t u; } c; c.f = f;
    uint32_t u = c.u;
    return (unsigned short)((u + 0x7FFFu + ((u >> 16) & 1u)) >> 16);
}

__device__ __forceinline__ void cvt8(const float* __restrict__ s, unsigned short* __restrict__ d) {
    f32x4 v0 = *(const f32x4*)s;
    f32x4 v1 = *(const f32x4*)(s + 4);
    u16x8 o;
    o[0] = f2bf_rne(v0[0]); o[1] = f2bf_rne(v0[1]); o[2] = f2bf_rne(v0[2]); o[3] = f2bf_rne(v0[3]);
    o[4] = f2bf_rne(v1[0]); o[5] = f2bf_rne(v1[1]); o[6] = f2bf_rne(v1[2]); o[7] = f2bf_rne(v1[3]);
    *(u16x8*)d = o;
}

// Single-array f32->bf16 (mid-ws fallback only)
__global__ __launch_bounds__(256)
void cvt_f32_bf16(const float* __restrict__ src, unsigned short* __restrict__ dst, long n) {
    long i = ((long)blockIdx.x * 256 + threadIdx.x) * 8;
    if (i < n) cvt8(src + i, dst + i);
}

// Fast-path converter: convert AND pack concat operands in one dispatch.
//   X[8192,1024] + state[8192,4096] -> XS bf16 [8192, 5120]
//   W_in[4096,1024] + W_rec[4096,4096] -> W1 bf16 [4096, 5120]
//   W_out[1024,4096] -> Wob bf16
#define NX8  ((long)BSZ * DIN / 8)     // 1048576
#define NS8  ((long)BSZ * HH / 8)      // 4194304
#define NWI8 ((long)HH * DIN / 8)      // 524288
#define NWR8 ((long)HH * HH / 8)       // 2097152
#define NWO8 ((long)DOUT * HH / 8)     // 524288
#define NCVT_BLOCKS 32768              // (NX8+NS8+NWI8+NWR8+NWO8)/256

__global__ __launch_bounds__(256)
void cvt_pack(const float* __restrict__ X, const float* __restrict__ S,
              const float* __restrict__ Wi, const float* __restrict__ Wr,
              const float* __restrict__ Wo,
              unsigned short* __restrict__ XS, unsigned short* __restrict__ W1,
              unsigned short* __restrict__ Wob) {
    long i = (long)blockIdx.x * 256 + threadIdx.x;
    if (i < NX8)  { long r = i >> 7, c = i & 127; cvt8(X + i * 8, XS + r * 5120 + c * 8); return; }
    i -= NX8;
    if (i < NS8)  { long r = i >> 9, c = i & 511; cvt8(S + i * 8, XS + r * 5120 + 1024 + c * 8); return; }
    i -= NS8;
    if (i < NWI8) { long r = i >> 7, c = i & 127; cvt8(Wi + i * 8, W1 + r * 5120 + c * 8); return; }
    i -= NWI8;
    if (i < NWR8) { long r = i >> 9, c = i & 511; cvt8(Wr + i * 8, W1 + r * 5120 + 1024 + c * 8); return; }
    i -= NWR8;
    if (i < NWO8) { cvt8(Wo + i * 8, Wob + i * 8); }
}

__device__ __forceinline__ void glds16(const unsigned short* __restrict__ gp, short* lp) {
    __builtin_amdgcn_global_load_lds(
        (const __attribute__((address_space(1))) uint32_t*)gp,
        (__attribute__((address_space(3))) uint32_t*)lp, 16, 0, 0);
}

__device__ __forceinline__ void glds16v(const unsigned short* __restrict__ gp, void* lp) {
    __builtin_amdgcn_global_load_lds(
        (const __attribute__((address_space(1))) uint32_t*)gp,
        (__attribute__((address_space(3))) uint32_t*)lp, 16, 0, 0);
}

// ============================================================================
// (MR*32) x 256 tile, BK=64, 8 waves (2M x 4N), barrier-minimized overlapped
// schedule: 2 barriers per K-tile, frag reads ride under MFMA.
//
// Per K-tile t (buffer C = t&1), per wave:
//   entry: bfr[C] (all B-frags of t) and af[0] (quad0 A-frags) already in regs
//          (pre-read during tile t-1's tail, after the stage-landed barrier).
//   p0:    issue A(t+1) stages -> buf C^1  (MR/2 glds)
//          issue B(t+2) stages -> buf C    (4 glds)
//          prefetch af[1] (quad1); MFMA quad0
//   p:     prefetch af[(p+1)&1]; MFMA quad p
//   end of phase NPH-2: vmcnt(4) (A(t+1)+B(t+1) landed; B(t+2) in flight),
//          s_barrier  (#A: ALL waves' slices landed -> cross-wave reads safe)
//   p=NPH-1: pre-read bfr[C^1] + af[0] for tile t+1 (from buf C^1);
//          MFMA quad NPH-1 (uses af[1], bfr[C] - no clash);
//          lgkmcnt(0) (own reads done) ; s_barrier (#B: safe to re-stage B region)
// Race analysis: B(t+2) stages (issued after #B of t-1... i.e. at t p0) land
// after all waves completed B(t) frag reads (lgkmcnt(0) before #B of t-1).
// A(t+1) stages target buf C^1, untouched by reads during tile t until the
// pre-read, which is after #A (vmcnt-confirmed by every wave). NT must be even.
// ============================================================================
template<int MR, int C>
__device__ __forceinline__ void ktile(
    const unsigned short* __restrict__ gA, size_t a64,
    const unsigned short* __restrict__ gB, size_t b64,
    int kA, int kB,
    const char* ArB, const char* BrB, char* wAB, char* wBB,
    int aoff, int boff,
    frag8 (&bfr)[2][4][2], frag8 (&af)[2][2][2], f32x4 (&acc)[MR][4])
{
    constexpr int NPH    = MR / 2;
    constexpr int ABYTES = MR * 4096;
    constexpr int BUFSTR = ABYTES + 32768;
    const char* Ar  = ArB + C * BUFSTR;
    const char* ArN = ArB + (C ^ 1) * BUFSTR;
    const char* BrN = BrB + (C ^ 1) * BUFSTR;
    char* wA = wAB + (C ^ 1) * BUFSTR;
    char* wB = wBB + C * BUFSTR;
    const unsigned short* gAk = gA + (size_t)kA * 64;
    const unsigned short* gBk = gB + (size_t)kB * 64;

#pragma unroll
    for (int i = 0; i < NPH; ++i)
        glds16v(gAk + (size_t)i * a64, wA + i * 8192);
#pragma unroll
    for (int i = 0; i < 4; ++i)
        glds16v(gBk + (size_t)i * b64, wB + i * 8192);

#pragma unroll
    for (int p = 0; p < NPH; ++p) {
        if (p < NPH - 1) {
            // prefetch next quad's A-frags (overlaps this quad's MFMA)
#pragma unroll
            for (int m2 = 0; m2 < 2; m2++)
#pragma unroll
                for (int ks = 0; ks < 2; ks++)
                    af[(p + 1) & 1][m2][ks] =
                        *(const frag8*)(Ar + ((p + 1) * 2 + m2) * 2048 + (aoff ^ (ks << 6)));
        } else {
            // last phase (after barrier #A): pre-read next tile's B + quad0-A
#pragma unroll
            for (int ni = 0; ni < 4; ni++)
#pragma unroll
                for (int ks = 0; ks < 2; ks++)
                    bfr[C ^ 1][ni][ks] =
                        *(const frag8*)(BrN + ni * 2048 + (boff ^ (ks << 6)));
#pragma unroll
            for (int m2 = 0; m2 < 2; m2++)
#pragma unroll
                for (int ks = 0; ks < 2; ks++)
                    af[0][m2][ks] =
                        *(const frag8*)(ArN + m2 * 2048 + (aoff ^ (ks << 6)));
        }
        __builtin_amdgcn_s_setprio(1);
#pragma unroll
        for (int m2 = 0; m2 < 2; m2++)
#pragma unroll
            for (int ni = 0; ni < 4; ni++)
#pragma unroll
                for (int ks = 0; ks < 2; ks++)
                    acc[p * 2 + m2][ni] = __builtin_amdgcn_mfma_f32_16x16x32_bf16(
                        af[p & 1][m2][ks], bfr[C][ni][ks], acc[p * 2 + m2][ni], 0, 0, 0);
        __builtin_amdgcn_s_setprio(0);
        if (p == NPH - 2) {
            asm volatile("s_waitcnt vmcnt(4)" ::: "memory");
            __builtin_amdgcn_sched_barrier(0);
            __builtin_amdgcn_s_barrier();
            __builtin_amdgcn_sched_barrier(0);
        }
    }
    asm volatile("s_waitcnt lgkmcnt(0)" ::: "memory");
    __builtin_amdgcn_sched_barrier(0);
    __builtin_amdgcn_s_barrier();
    __builtin_amdgcn_sched_barrier(0);
}

template<int MR>
__global__ __launch_bounds__(512, 2)
void gemm256_relu(const unsigned short* __restrict__ A, int lda,
                  const unsigned short* __restrict__ B, int ldb, int K,
                  const float* __restrict__ bias1, const float* __restrict__ bias2,
                  float* __restrict__ C, unsigned short* __restrict__ Cb, int ncols) {
    extern __shared__ char lds[];
    constexpr int ABYTES = MR * 4096;
    constexpr int BUFSTR = ABYTES + 32768;

    const int tid  = threadIdx.x;
    const int wave = tid >> 6, lane = tid & 63;
    const int quad = lane >> 4, l16 = lane & 15;
    const int wm2  = wave >> 2, wn4 = wave & 3;     // 2M x 4N wave grid
    const int tile_m = blockIdx.y * (MR * 32);
    const int tile_n = blockIdx.x * 256;
    const int NT = K >> 6;                          // K-tiles; must be even

    // Staging source (per-thread): slot tid -> row r0 (+64 per group), swizzled chunk c0
    const int r0 = tid >> 3;
    const int c0 = (tid & 7) ^ (r0 & 7);
    const unsigned short* gA = A + (size_t)(tile_m + r0) * lda + c0 * 8;
    const unsigned short* gB = B + (size_t)(tile_n + r0) * ldb + c0 * 8;
    const size_t a64 = (size_t)64 * lda, b64 = (size_t)64 * ldb;

    // Read-side per-lane byte offsets: row*128 + swizzled chunk*16
    const int swz  = (quad ^ (l16 & 7)) << 4;
    const int aoff = l16 * 128 + swz;
    const int boff = ((wn4 & 1) * 64 + l16) * 128 + swz;
    const char* ArB = lds + wm2 * (MR * 2048);               // wave's A half, buf0
    const char* BrB = lds + ABYTES + (wn4 >> 1) * 16384;     // wave's B half, buf0
    char* wAB = lds + wave * 1024;                           // wave-uniform stage bases
    char* wBB = lds + ABYTES + wave * 1024;

    frag8 bfr[2][4][2];
    frag8 af[2][2][2];
    f32x4 acc[MR][4] = {};

    // Prologue: stage tile0 (A,B)->buf0 and tile1 B->buf1
#pragma unroll
    for (int i = 0; i < MR / 2; ++i) glds16v(gA + (size_t)i * a64, wAB + i * 8192);
#pragma unroll
    for (int i = 0; i < 4; ++i)      glds16v(gB + (size_t)i * b64, wBB + i * 8192);
#pragma unroll
    for (int i = 0; i < 4; ++i)      glds16v(gB + 64 + (size_t)i * b64, wBB + BUFSTR + i * 8192);
    asm volatile("s_waitcnt vmcnt(4)" ::: "memory");   // tile0 landed; tile1-B in flight
    __builtin_amdgcn_sched_barrier(0);
    __builtin_amdgcn_s_barrier();
    __builtin_amdgcn_sched_barrier(0);
    // pre-read tile0 frags (buf0)
#pragma unroll
    for (int ni = 0; ni < 4; ni++)
#pragma unroll
        for (int ks = 0; ks < 2; ks++)
            bfr[0][ni][ks] = *(const frag8*)(BrB + ni * 2048 + (boff ^ (ks << 6)));
#pragma unroll
    for (int m2 = 0; m2 < 2; m2++)
#pragma unroll
        for (int ks = 0; ks < 2; ks++)
            af[0][m2][ks] = *(const frag8*)(ArB + m2 * 2048 + (aoff ^ (ks << 6)));
    asm volatile("s_waitcnt lgkmcnt(0)" ::: "memory");
    __builtin_amdgcn_sched_barrier(0);
    __builtin_amdgcn_s_barrier();     // all waves done reading tile0 B -> re-stage ok
    __builtin_amdgcn_sched_barrier(0);

    for (int kt = 0; kt < NT; kt += 2) {
        const int kA0 = kt + 1;                               // always < NT (NT even)
        const int kB0 = (kt + 2 < NT) ? kt + 2 : 0;           // wrap: harmless
        ktile<MR, 0>(gA, a64, gB, b64, kA0, kB0, ArB, BrB, wAB, wBB, aoff, boff, bfr, af, acc);
        const int kA1 = (kt + 2 < NT) ? kt + 2 : 0;
        const int kB1 = (kt + 3 < NT) ? kt + 3 : 1;
        ktile<MR, 1>(gA, a64, gB, b64, kA1, kB1, ArB, BrB, wAB, wBB, aoff, boff, bfr, af, acc);
    }

    // Epilogue. C/D layout (verified m89/m91): n = l16, m = quad*4 + reg.
#pragma unroll
    for (int ni = 0; ni < 4; ni++) {
        const int n = tile_n + wn4 * 64 + ni * 16 + l16;
        float bv = bias1[n];
        if (bias2) bv += bias2[n];
#pragma unroll
        for (int mi = 0; mi < MR; mi++) {
            const int m0 = tile_m + wm2 * (MR * 16) + mi * 16 + quad * 4;
#pragma unroll
            for (int r = 0; r < 4; r++) {
                float v = acc[mi][ni][r] + bv;
                v = v > 0.f ? v : 0.f;
                const size_t idx = (size_t)(m0 + r) * ncols + n;
                C[idx] = v;
                if (Cb) Cb[idx] = f2bf_rne(v);
            }
        }
    }
}

// ============================================================================
// OLD 128x128 kernel, kept verbatim for mid/no-ws fallback paths.
// ============================================================================
template <bool A_BF16, bool B_BF16>
__global__ __launch_bounds__(256)
void gemm_bt_relu(const void* __restrict__ A1, int lda1,
                  const void* __restrict__ A2, int lda2,
                  const void* __restrict__ B1, int ldb1,
                  const void* __restrict__ B2, int ldb2,
                  int Ksplit, int K,
                  const float* __restrict__ bias1, const float* __restrict__ bias2,
                  float* __restrict__ C, unsigned short* __restrict__ Cb, int N) {
    __shared__ short As[BM * BK];
    __shared__ short Bs[BN * BK];

    const int tid    = threadIdx.x;
    const int tile_m = blockIdx.y * BM;
    const int tile_n = blockIdx.x * BN;
    const int wave = tid >> 6, lane = tid & 63;
    const int quad = lane >> 4, l16 = lane & 15;
    const int wm = (wave >> 1) * 64;
    const int wn = (wave & 1) * 64;
    const int sr = tid >> 2;
    const int sc = (tid & 3) * 8;

    short* ldsA0 = &As[tid * 8]; short* ldsA1 = &As[(256 + tid) * 8];
    short* ldsB0 = &Bs[tid * 8]; short* ldsB1 = &Bs[(256 + tid) * 8];

    f32x4 acc[4][4] = {};

    for (int phase = 0; phase < 2; ++phase) {
        const int kmax = phase ? (K - Ksplit) : Ksplit;
        if (kmax <= 0) continue;
        const void* Ap = phase ? A2 : A1; const int la = phase ? lda2 : lda1;
        const void* Bp = phase ? B2 : B1; const int lb = phase ? ldb2 : ldb1;

        const unsigned short *ga = nullptr, *gb = nullptr;
        const float *fa = nullptr, *fb = nullptr;
        if (A_BF16) ga = (const unsigned short*)Ap + (size_t)(tile_m + sr) * la + sc;
        else        fa = (const float*)Ap          + (size_t)(tile_m + sr) * la + sc;
        if (B_BF16) gb = (const unsigned short*)Bp + (size_t)(tile_n + sr) * lb + sc;
        else        fb = (const float*)Bp          + (size_t)(tile_n + sr) * lb + sc;
        const size_t la64 = (size_t)64 * la, lb64 = (size_t)64 * lb;

        for (int kk = 0; kk < kmax; kk += BK) {
            __syncthreads();
            if (A_BF16) {
                glds16(ga, ldsA0); glds16(ga + la64, ldsA1); ga += BK;
            } else {
                unsigned short t0[8], t1[8];
                cvt8(fa, t0); cvt8(fa + la64, t1); fa += BK;
                *(u16x8*)ldsA0 = *(u16x8*)t0; *(u16x8*)ldsA1 = *(u16x8*)t1;
            }
            if (B_BF16) {
                glds16(gb, ldsB0); glds16(gb + lb64, ldsB1); gb += BK;
            } else {
                unsigned short t0[8], t1[8];
                cvt8(fb, t0); cvt8(fb + lb64, t1); fb += BK;
                *(u16x8*)ldsB0 = *(u16x8*)t0; *(u16x8*)ldsB1 = *(u16x8*)t1;
            }
            __syncthreads();

            frag8 af2[4], bfr[4];
#pragma unroll
            for (int i = 0; i < 4; i++)
                af2[i] = *(const frag8*)&As[(wm + i * 16 + l16) * BK + quad * 8];
#pragma unroll
            for (int i = 0; i < 4; i++)
                bfr[i] = *(const frag8*)&Bs[(wn + i * 16 + l16) * BK + quad * 8];
#pragma unroll
            for (int mi = 0; mi < 4; mi++)
#pragma unroll
                for (int ni = 0; ni < 4; ni++)
                    acc[mi][ni] = __builtin_amdgcn_mfma_f32_16x16x32_bf16(
                        af2[mi], bfr[ni], acc[mi][ni], 0, 0, 0);
        }
    }

#pragma unroll
    for (int mi = 0; mi < 4; mi++) {
        const int m0 = tile_m + wm + mi * 16 + quad * 4;
#pragma unroll
        for (int ni = 0; ni < 4; ni++) {
            const int n = tile_n + wn + ni * 16 + l16;
            float bv = bias1[n];
            if (bias2) bv += bias2[n];
#pragma unroll
            for (int r = 0; r < 4; r++) {
                float v = acc[mi][ni][r] + bv;
                v = v > 0.f ? v : 0.f;
                const size_t idx = (size_t)(m0 + r) * N + n;
                C[idx] = v;
                if (Cb) Cb[idx] = f2bf_rne(v);
            }
        }
    }
}

extern "C" void kernel_launch(void* const* d_in, const int* in_sizes, int n_in,
                              void* d_out, int out_size, void* d_ws, size_t ws_size,
                              hipStream_t stream) {
    const float* X     = (const float*)d_in[0];
    const float* state = (const float*)d_in[1];
    const float* W_in  = (const float*)d_in[2];
    const float* b_in  = (const float*)d_in[3];
    const float* W_rec = (const float*)d_in[4];
    const float* b_rec = (const float*)d_in[5];
    const float* W_out = (const float*)d_in[6];
    const float* b_out = (const float*)d_in[7];

    float* out       = (float*)d_out;                       // [8192,1024]
    float* new_state = out + (size_t)BSZ * DOUT;            // [8192,4096]

    const size_t nS = (size_t)BSZ * HH;
    const size_t nWout = (size_t)DOUT * HH;

    // Fast-path ws layout (all bf16, packed concat):
    //   XS [8192,5120] | W1 [4096,5120] | Wob [1024,4096] | NSb [8192,4096]
    const size_t offXS = 0;
    const size_t offW1 = offXS + (size_t)BSZ * (DIN + HH) * 2;   //  83,886,080
    const size_t offWo = offW1 + (size_t)HH  * (DIN + HH) * 2;   // 125,829,120
    const size_t offNS = offWo + (size_t)DOUT * HH * 2;          // 134,217,728
    const size_t need_full = offNS + nS * 2;                     // 201,326,592
    const size_t need_mid = nS * 2 + nWout * 2;                  // ~72 MiB

    char* ws = (char*)d_ws;
    const dim3 blk(256);

    if (ws_size >= need_full) {
        unsigned short* XSb = (unsigned short*)(ws + offXS);
        unsigned short* W1b = (unsigned short*)(ws + offW1);
        unsigned short* Wob = (unsigned short*)(ws + offWo);
        unsigned short* NSb = (unsigned short*)(ws + offNS);

        static bool s_attr = false;
        if (!s_attr) {
            hipFuncSetAttribute(reinterpret_cast<const void*>(gemm256_relu<8>),
                                hipFuncAttributeMaxDynamicSharedMemorySize, 131072);
            hipFuncSetAttribute(reinterpret_cast<const void*>(gemm256_relu<4>),
                                hipFuncAttributeMaxDynamicSharedMemorySize, 98304);
            s_attr = true;
        }

        cvt_pack<<<dim3(NCVT_BLOCKS), blk, 0, stream>>>(
            X, state, W_in, W_rec, W_out, XSb, W1b, Wob);
        // gemm1: new_state = relu(XS @ W1^T + b_in + b_rec)   [8192 x 4096], K=5120
        gemm256_relu<8><<<dim3(HH / 256, BSZ / 256), dim3(512), 131072, stream>>>(
            XSb, DIN + HH, W1b, DIN + HH, DIN + HH, b_in, b_rec, new_state, NSb, HH);
        // gemm2: out = relu(NS @ W_out^T + b_out)  [8192 x 1024], K=4096, 128x256 tile
        gemm256_relu<4><<<dim3(DOUT / 256, BSZ / 128), dim3(512), 98304, stream>>>(
            NSb, HH, Wob, HH, HH, b_out, nullptr, out, nullptr, DOUT);
    } else if (ws_size >= need_mid) {
        const dim3 g1(HH / BN, BSZ / BM);
        const dim3 g2(DOUT / BN, BSZ / BM);
        unsigned short* NSb   = (unsigned short*)ws;
        unsigned short* Woutb = (unsigned short*)(ws + nS * 2);
        cvt_f32_bf16<<<dim3((unsigned)((nWout / 8 + 255) / 256)), blk, 0, stream>>>(
            W_out, Woutb, (long)nWout);
        gemm_bt_relu<false, false><<<g1, blk, 0, stream>>>(
            X, DIN, state, HH, W_in, DIN, W_rec, HH, DIN, DIN + HH,
            b_in, b_rec, new_state, NSb, HH);
        gemm_bt_relu<true, true><<<g2, blk, 0, stream>>>(
            NSb, HH, NSb, HH, Woutb, HH, Woutb, HH, HH, HH,
            b_out, nullptr, out, nullptr, DOUT);
    } else {
        const dim3 g1(HH / BN, BSZ / BM);
        const dim3 g2(DOUT / BN, BSZ / BM);
        gemm_bt_relu<false, false><<<g1, blk, 0, stream>>>(
            X, DIN, state, HH, W_in, DIN, W_rec, HH, DIN, DIN + HH,
            b_in, b_rec, new_state, nullptr, HH);
        gemm_bt_relu<false, false><<<g2, blk, 0, stream>>>(
            new_state, HH, new_state, HH, W_out, HH, W_out, HH, HH, HH,
            b_out, nullptr, out, nullptr, DOUT);
    }
}

// Round 3
// 745.496 us; speedup vs baseline: 1.2040x; 1.2040x over previous
//
#include <hip/hip_runtime.h>
#include <hip/hip_bf16.h>
#include <stdint.h>
#include <stddef.h>

// Problem dims (fixed by reference)
#define BSZ  8192
#define DIN  1024
#define HH   4096
#define DOUT 1024

// Old-kernel GEMM tile config (kept for fallback paths)
#define BM 128
#define BN 128
#define BK 32

typedef __attribute__((ext_vector_type(8))) short   frag8;   // 8 bf16 (4 VGPRs)
typedef __attribute__((ext_vector_type(4))) float   f32x4;   // MFMA C/D
typedef __attribute__((ext_vector_type(8))) unsigned short u16x8;

__device__ __forceinline__ unsigned short f2bf_rne(float f) {
    union { float f; uint32_t u; } c; c.f = f;
    uint32_t u = c.u;
    return (unsigned short)((u + 0x7FFFu + ((u >> 16) & 1u)) >> 16);
}

__device__ __forceinline__ void cvt8(const float* __restrict__ s, unsigned short* __restrict__ d) {
    f32x4 v0 = *(const f32x4*)s;
    f32x4 v1 = *(const f32x4*)(s + 4);
    u16x8 o;
    o[0] = f2bf_rne(v0[0]); o[1] = f2bf_rne(v0[1]); o[2] = f2bf_rne(v0[2]); o[3] = f2bf_rne(v0[3]);
    o[4] = f2bf_rne(v1[0]); o[5] = f2bf_rne(v1[1]); o[6] = f2bf_rne(v1[2]); o[7] = f2bf_rne(v1[3]);
    *(u16x8*)d = o;
}

// Single-array f32->bf16 (mid-ws fallback only)
__global__ __launch_bounds__(256)
void cvt_f32_bf16(const float* __restrict__ src, unsigned short* __restrict__ dst, long n) {
    long i = ((long)blockIdx.x * 256 + threadIdx.x) * 8;
    if (i < n) cvt8(src + i, dst + i);
}

// Fast-path converter: convert AND pack concat operands in one dispatch.
//   X[8192,1024] + state[8192,4096] -> XS bf16 [8192, 5120]
//   W_in[4096,1024] + W_rec[4096,4096] -> W1 bf16 [4096, 5120]
//   W_out[1024,4096] -> Wob bf16
#define NX8  ((long)BSZ * DIN / 8)     // 1048576
#define NS8  ((long)BSZ * HH / 8)      // 4194304
#define NWI8 ((long)HH * DIN / 8)      // 524288
#define NWR8 ((long)HH * HH / 8)      // 2097152
#define NWO8 ((long)DOUT * HH / 8)     // 524288
#define NCVT_BLOCKS 32768              // (NX8+NS8+NWI8+NWR8+NWO8)/256

__global__ __launch_bounds__(256)
void cvt_pack(const float* __restrict__ X, const float* __restrict__ S,
              const float* __restrict__ Wi, const float* __restrict__ Wr,
              const float* __restrict__ Wo,
              unsigned short* __restrict__ XS, unsigned short* __restrict__ W1,
              unsigned short* __restrict__ Wob) {
    long i = (long)blockIdx.x * 256 + threadIdx.x;
    if (i < NX8)  { long r = i >> 7, c = i & 127; cvt8(X + i * 8, XS + r * 5120 + c * 8); return; }
    i -= NX8;
    if (i < NS8)  { long r = i >> 9, c = i & 511; cvt8(S + i * 8, XS + r * 5120 + 1024 + c * 8); return; }
    i -= NS8;
    if (i < NWI8) { long r = i >> 7, c = i & 127; cvt8(Wi + i * 8, W1 + r * 5120 + c * 8); return; }
    i -= NWI8;
    if (i < NWR8) { long r = i >> 9, c = i & 511; cvt8(Wr + i * 8, W1 + r * 5120 + 1024 + c * 8); return; }
    i -= NWR8;
    if (i < NWO8) { cvt8(Wo + i * 8, Wob + i * 8); }
}

__device__ __forceinline__ void glds16(const unsigned short* __restrict__ gp, short* lp) {
    __builtin_amdgcn_global_load_lds(
        (const __attribute__((address_space(1))) uint32_t*)gp,
        (__attribute__((address_space(3))) uint32_t*)lp, 16, 0, 0);
}

__device__ __forceinline__ void glds16v(const unsigned short* __restrict__ gp, void* lp) {
    __builtin_amdgcn_global_load_lds(
        (const __attribute__((address_space(1))) uint32_t*)gp,
        (__attribute__((address_space(3))) uint32_t*)lp, 16, 0, 0);
}

// ============================================================================
// (MR*32) x 256 tile, BK=64, 8 waves (2M x 4N), 8-phase counted-vmcnt GEMM.
// This is the PROVEN round-1 schedule, templated on MR (MR=8 instantiation is
// instruction-identical to round 1's 256x256 kernel).
//
// LDS (2 bufs): buf b: A region (MR*4 KiB) | B region (32 KiB). XOR-swizzled
// (chunk ^= row&7), inverse applied to the gload_lds GLOBAL src addr, LDS dest
// linear (rule #21).
//
// Schedule per K-tile kt (4 phases, phase p = m-group p, MPP=MR/4 m-frags each):
//   p0: read all 8 B-frags (held in regs) + phase-0 A-frags;
//       stage A(kt+1) -> other buf        [MR/2 loads]
//   p1: read A-frags p1; stage B(kt+2) h0 -> THIS buf    [2 loads]
//   p2: read A-frags p2; stage B(kt+2) h1 -> THIS buf    [2 loads]
//   p3: read A-frags p3; s_waitcnt vmcnt(4) (A(kt+1)+B(kt+1) landed; B(kt+2)'s
//       4 loads stay in flight -> never drains to 0 in the loop)
//   each phase: {reads; stages; s_barrier; setprio(1); MFMAs; setprio(0);
//               [vmcnt]; s_barrier}
// ============================================================================
template<int MR, int C>
__device__ __forceinline__ void ktile_group(
    int kA, int kB,
    const unsigned short* __restrict__ gA, size_t a64,
    const unsigned short* __restrict__ gB, size_t b64,
    const char* Ar0, const char* Br0, char* ldsw,
    int aoff, int boff, f32x4 (&acc)[MR][4])
{
    constexpr int MPP    = MR / 4;            // m-frags per phase
    constexpr int ABYTES = MR * 4096;
    constexpr int BUFSTR = ABYTES + 32768;
    const char* Ar = Ar0 + C * BUFSTR;
    const char* Br = Br0 + C * BUFSTR;
    char* wA = ldsw + (C ^ 1) * BUFSTR;          // A region of the other buffer
    char* wB = ldsw + C * BUFSTR + ABYTES;       // B region of this (read) buffer
    const unsigned short* gAk = gA + (size_t)kA * 64;
    const unsigned short* gBk = gB + (size_t)kB * 64;

    frag8 bfr[4][2];
    frag8 af[MPP][2];
#pragma unroll
    for (int p = 0; p < 4; ++p) {
        if (p == 0) {
#pragma unroll
            for (int ni = 0; ni < 4; ni++)
#pragma unroll
                for (int ks = 0; ks < 2; ks++)
                    bfr[ni][ks] = *(const frag8*)(Br + ni * 2048 + (boff ^ (ks << 6)));
        }
#pragma unroll
        for (int m2 = 0; m2 < MPP; m2++)
#pragma unroll
            for (int ks = 0; ks < 2; ks++)
                af[m2][ks] = *(const frag8*)(Ar + (p * MPP + m2) * 2048 + (aoff ^ (ks << 6)));

        if (p == 0) {
#pragma unroll
            for (int i = 0; i < MR / 2; ++i)
                glds16v(gAk + (size_t)i * a64, wA + i * 8192);
        } else if (p == 1) {
            glds16v(gBk,           wB);
            glds16v(gBk + b64,     wB + 8192);
        } else if (p == 2) {
            glds16v(gBk + 2 * b64, wB + 16384);
            glds16v(gBk + 3 * b64, wB + 16384 + 8192);
        }

        __builtin_amdgcn_s_barrier();
        __builtin_amdgcn_s_setprio(1);
#pragma unroll
        for (int m2 = 0; m2 < MPP; m2++)
#pragma unroll
            for (int ni = 0; ni < 4; ni++)
#pragma unroll
                for (int ks = 0; ks < 2; ks++)
                    acc[p * MPP + m2][ni] = __builtin_amdgcn_mfma_f32_16x16x32_bf16(
                        af[m2][ks], bfr[ni][ks], acc[p * MPP + m2][ni], 0, 0, 0);
        __builtin_amdgcn_s_setprio(0);
        if (p == 3) asm volatile("s_waitcnt vmcnt(4)" ::: "memory");
        __builtin_amdgcn_s_barrier();
    }
}

template<int MR>
__global__ __launch_bounds__(512, 2)
void gemm256_relu(const unsigned short* __restrict__ A, int lda,
                  const unsigned short* __restrict__ B, int ldb, int K,
                  const float* __restrict__ bias1, const float* __restrict__ bias2,
                  float* __restrict__ C, unsigned short* __restrict__ Cb, int ncols) {
    extern __shared__ char lds[];
    constexpr int ABYTES = MR * 4096;
    constexpr int BUFSTR = ABYTES + 32768;

    const int tid  = threadIdx.x;
    const int wave = tid >> 6, lane = tid & 63;
    const int quad = lane >> 4, l16 = lane & 15;
    const int wm2  = wave >> 2, wn4 = wave & 3;     // 2M x 4N wave grid
    const int tile_m = blockIdx.y * (MR * 32);
    const int tile_n = blockIdx.x * 256;
    const int NT = K >> 6;                          // K-tiles (even for all our shapes)

    // Staging source (per-thread): slot tid -> row r0, swizzled chunk c0
    const int r0 = tid >> 3;
    const int c0 = (tid & 7) ^ (r0 & 7);
    const unsigned short* gA = A + (size_t)(tile_m + r0) * lda + c0 * 8;
    const unsigned short* gB = B + (size_t)(tile_n + r0) * ldb + c0 * 8;
    const size_t a64 = (size_t)64 * lda, b64 = (size_t)64 * ldb;

    // Read-side per-lane byte offsets (within a region): row*128 + swizzled chunk*16
    const int swz  = (quad ^ (l16 & 7)) << 4;
    const int aoff = l16 * 128 + swz;
    const int boff = ((wn4 & 1) * 64 + l16) * 128 + swz;
    const char* Ar0 = lds + wm2 * (MR * 2048);               // wave's A half, buf0
    const char* Br0 = lds + ABYTES + (wn4 >> 1) * 16384;     // wave's B half, buf0
    char* ldsw = lds + wave * 1024;                          // wave-uniform stage base

    // Prologue: T0 (A+B) -> buf0; B of T1 -> buf1. vmcnt(4) = T0 landed,
    // B(T1) left in flight (steady-state invariant: 4 loads outstanding at barriers).
#pragma unroll
    for (int i = 0; i < MR / 2; ++i)
        glds16v(gA + (size_t)i * a64, ldsw + i * 8192);
#pragma unroll
    for (int i = 0; i < 4; ++i)
        glds16v(gB + (size_t)i * b64, ldsw + ABYTES + i * 8192);
#pragma unroll
    for (int i = 0; i < 4; ++i)
        glds16v(gB + 64 + (size_t)i * b64, ldsw + BUFSTR + ABYTES + i * 8192);
    asm volatile("s_waitcnt vmcnt(4)" ::: "memory");
    __builtin_amdgcn_s_barrier();

    f32x4 acc[MR][4] = {};

    for (int kt = 0; kt < NT; kt += 2) {
        int kA0 = kt + 1;                                  // < NT always here
        int kB0 = kt + 2; if (kB0 >= NT) kB0 -= NT;        // wrap: harmless extra load
        ktile_group<MR, 0>(kA0, kB0, gA, a64, gB, b64, Ar0, Br0, ldsw, aoff, boff, acc);
        int kA1 = kt + 2; if (kA1 >= NT) kA1 -= NT;
        int kB1 = kt + 3; if (kB1 >= NT) kB1 -= NT;
        ktile_group<MR, 1>(kA1, kB1, gA, a64, gB, b64, Ar0, Br0, ldsw, aoff, boff, acc);
    }

    // Epilogue. C/D layout (verified m89/m91): n = l16, m = quad*4 + reg.
#pragma unroll
    for (int ni = 0; ni < 4; ni++) {
        const int n = tile_n + wn4 * 64 + ni * 16 + l16;
        float bv = bias1[n];
        if (bias2) bv += bias2[n];
#pragma unroll
        for (int mi = 0; mi < MR; mi++) {
            const int m0 = tile_m + wm2 * (MR * 16) + mi * 16 + quad * 4;
#pragma unroll
            for (int r = 0; r < 4; r++) {
                float v = acc[mi][ni][r] + bv;
                v = v > 0.f ? v : 0.f;
                const size_t idx = (size_t)(m0 + r) * ncols + n;
                C[idx] = v;
                if (Cb) Cb[idx] = f2bf_rne(v);
            }
        }
    }
}

// ============================================================================
// OLD 128x128 kernel, kept verbatim for mid/no-ws fallback paths.
// ============================================================================
template <bool A_BF16, bool B_BF16>
__global__ __launch_bounds__(256)
void gemm_bt_relu(const void* __restrict__ A1, int lda1,
                  const void* __restrict__ A2, int lda2,
                  const void* __restrict__ B1, int ldb1,
                  const void* __restrict__ B2, int ldb2,
                  int Ksplit, int K,
                  const float* __restrict__ bias1, const float* __restrict__ bias2,
                  float* __restrict__ C, unsigned short* __restrict__ Cb, int N) {
    __shared__ short As[BM * BK];
    __shared__ short Bs[BN * BK];

    const int tid    = threadIdx.x;
    const int tile_m = blockIdx.y * BM;
    const int tile_n = blockIdx.x * BN;
    const int wave = tid >> 6, lane = tid & 63;
    const int quad = lane >> 4, l16 = lane & 15;
    const int wm = (wave >> 1) * 64;
    const int wn = (wave & 1) * 64;
    const int sr = tid >> 2;
    const int sc = (tid & 3) * 8;

    short* ldsA0 = &As[tid * 8]; short* ldsA1 = &As[(256 + tid) * 8];
    short* ldsB0 = &Bs[tid * 8]; short* ldsB1 = &Bs[(256 + tid) * 8];

    f32x4 acc[4][4] = {};

    for (int phase = 0; phase < 2; ++phase) {
        const int kmax = phase ? (K - Ksplit) : Ksplit;
        if (kmax <= 0) continue;
        const void* Ap = phase ? A2 : A1; const int la = phase ? lda2 : lda1;
        const void* Bp = phase ? B2 : B1; const int lb = phase ? ldb2 : ldb1;

        const unsigned short *ga = nullptr, *gb = nullptr;
        const float *fa = nullptr, *fb = nullptr;
        if (A_BF16) ga = (const unsigned short*)Ap + (size_t)(tile_m + sr) * la + sc;
        else        fa = (const float*)Ap          + (size_t)(tile_m + sr) * la + sc;
        if (B_BF16) gb = (const unsigned short*)Bp + (size_t)(tile_n + sr) * lb + sc;
        else        fb = (const float*)Bp          + (size_t)(tile_n + sr) * lb + sc;
        const size_t la64 = (size_t)64 * la, lb64 = (size_t)64 * lb;

        for (int kk = 0; kk < kmax; kk += BK) {
            __syncthreads();
            if (A_BF16) {
                glds16(ga, ldsA0); glds16(ga + la64, ldsA1); ga += BK;
            } else {
                unsigned short t0[8], t1[8];
                cvt8(fa, t0); cvt8(fa + la64, t1); fa += BK;
                *(u16x8*)ldsA0 = *(u16x8*)t0; *(u16x8*)ldsA1 = *(u16x8*)t1;
            }
            if (B_BF16) {
                glds16(gb, ldsB0); glds16(gb + lb64, ldsB1); gb += BK;
            } else {
                unsigned short t0[8], t1[8];
                cvt8(fb, t0); cvt8(fb + lb64, t1); fb += BK;
                *(u16x8*)ldsB0 = *(u16x8*)t0; *(u16x8*)ldsB1 = *(u16x8*)t1;
            }
            __syncthreads();

            frag8 af2[4], bfr[4];
#pragma unroll
            for (int i = 0; i < 4; i++)
                af2[i] = *(const frag8*)&As[(wm + i * 16 + l16) * BK + quad * 8];
#pragma unroll
            for (int i = 0; i < 4; i++)
                bfr[i] = *(const frag8*)&Bs[(wn + i * 16 + l16) * BK + quad * 8];
#pragma unroll
            for (int mi = 0; mi < 4; mi++)
#pragma unroll
                for (int ni = 0; ni < 4; ni++)
                    acc[mi][ni] = __builtin_amdgcn_mfma_f32_16x16x32_bf16(
                        af2[mi], bfr[ni], acc[mi][ni], 0, 0, 0);
        }
    }

#pragma unroll
    for (int mi = 0; mi < 4; mi++) {
        const int m0 = tile_m + wm + mi * 16 + quad * 4;
#pragma unroll
        for (int ni = 0; ni < 4; ni++) {
            const int n = tile_n + wn + ni * 16 + l16;
            float bv = bias1[n];
            if (bias2) bv += bias2[n];
#pragma unroll
            for (int r = 0; r < 4; r++) {
                float v = acc[mi][ni][r] + bv;
                v = v > 0.f ? v : 0.f;
                const size_t idx = (size_t)(m0 + r) * N + n;
                C[idx] = v;
                if (Cb) Cb[idx] = f2bf_rne(v);
            }
        }
    }
}

extern "C" void kernel_launch(void* const* d_in, const int* in_sizes, int n_in,
                              void* d_out, int out_size, void* d_ws, size_t ws_size,
                              hipStream_t stream) {
    const float* X     = (const float*)d_in[0];
    const float* state = (const float*)d_in[1];
    const float* W_in  = (const float*)d_in[2];
    const float* b_in  = (const float*)d_in[3];
    const float* W_rec = (const float*)d_in[4];
    const float* b_rec = (const float*)d_in[5];
    const float* W_out = (const float*)d_in[6];
    const float* b_out = (const float*)d_in[7];

    float* out       = (float*)d_out;                       // [8192,1024]
    float* new_state = out + (size_t)BSZ * DOUT;            // [8192,4096]

    const size_t nS = (size_t)BSZ * HH;
    const size_t nWout = (size_t)DOUT * HH;

    // Fast-path ws layout (all bf16, packed concat):
    //   XS [8192,5120] | W1 [4096,5120] | Wob [1024,4096] | NSb [8192,4096]
    const size_t offXS = 0;
    const size_t offW1 = offXS + (size_t)BSZ * (DIN + HH) * 2;   //  83,886,080
    const size_t offWo = offW1 + (size_t)HH  * (DIN + HH) * 2;   // 125,829,120
    const size_t offNS = offWo + (size_t)DOUT * HH * 2;          // 134,217,728
    const size_t need_full = offNS + nS * 2;                     // 201,326,592
    const size_t need_mid = nS * 2 + nWout * 2;                  // ~72 MiB

    char* ws = (char*)d_ws;
    const dim3 blk(256);

    if (ws_size >= need_full) {
        unsigned short* XSb = (unsigned short*)(ws + offXS);
        unsigned short* W1b = (unsigned short*)(ws + offW1);
        unsigned short* Wob = (unsigned short*)(ws + offWo);
        unsigned short* NSb = (unsigned short*)(ws + offNS);

        static bool s_attr = false;
        if (!s_attr) {
            hipFuncSetAttribute(reinterpret_cast<const void*>(gemm256_relu<8>),
                                hipFuncAttributeMaxDynamicSharedMemorySize, 131072);
            hipFuncSetAttribute(reinterpret_cast<const void*>(gemm256_relu<4>),
                                hipFuncAttributeMaxDynamicSharedMemorySize, 98304);
            s_attr = true;
        }

        cvt_pack<<<dim3(NCVT_BLOCKS), blk, 0, stream>>>(
            X, state, W_in, W_rec, W_out, XSb, W1b, Wob);
        // gemm1: new_state = relu(XS @ W1^T + b_in + b_rec)   [8192 x 4096], K=5120
        // 256x256 tile, 512 WGs (round-1 proven config, unchanged)
        gemm256_relu<8><<<dim3(HH / 256, BSZ / 256), dim3(512), 131072, stream>>>(
            XSb, DIN + HH, W1b, DIN + HH, DIN + HH, b_in, b_rec, new_state, NSb, HH);
        // gemm2: out = relu(NS @ W_out^T + b_out)  [8192 x 1024], K=4096
        // 128x256 tile -> 256 WGs (all CUs busy), same proven schedule
        gemm256_relu<4><<<dim3(DOUT / 256, BSZ / 128), dim3(512), 98304, stream>>>(
            NSb, HH, Wob, HH, HH, b_out, nullptr, out, nullptr, DOUT);
    } else if (ws_size >= need_mid) {
        const dim3 g1(HH / BN, BSZ / BM);
        const dim3 g2(DOUT / BN, BSZ / BM);
        unsigned short* NSb   = (unsigned short*)ws;
        unsigned short* Woutb = (unsigned short*)(ws + nS * 2);
        cvt_f32_bf16<<<dim3((unsigned)((nWout / 8 + 255) / 256)), blk, 0, stream>>>(
            W_out, Woutb, (long)nWout);
        gemm_bt_relu<false, false><<<g1, blk, 0, stream>>>(
            X, DIN, state, HH, W_in, DIN, W_rec, HH, DIN, DIN + HH,
            b_in, b_rec, new_state, NSb, HH);
        gemm_bt_relu<true, true><<<g2, blk, 0, stream>>>(
            NSb, HH, NSb, HH, Woutb, HH, Woutb, HH, HH, HH,
            b_out, nullptr, out, nullptr, DOUT);
    } else {
        const dim3 g1(HH / BN, BSZ / BM);
        const dim3 g2(DOUT / BN, BSZ / BM);
        gemm_bt_relu<false, false><<<g1, blk, 0, stream>>>(
            X, DIN, state, HH, W_in, DIN, W_rec, HH, DIN, DIN + HH,
            b_in, b_rec, new_state, nullptr, HH);
        gemm_bt_relu<false, false><<<g2, blk, 0, stream>>>(
            new_state, HH, new_state, HH, W_out, HH, W_out, HH, HH, HH,
            b_out, nullptr, out, nullptr, DOUT);
    }
}